// Round 10
// baseline (7150.811 us; speedup 1.0000x reference)
//
#include <hip/hip_runtime.h>

#define D 128
#define NT 10    // edge types
#define NL 4     // layers
#define SCH 1024 // nodes per scan chunk
#define NMAT 57
#define MATSZ 32768  // shorts per converted matrix (hi 16384 + lo 16384)

typedef __attribute__((ext_vector_type(8))) short bf16x8;
typedef __attribute__((ext_vector_type(4))) float f32x4;

struct CvtTab { const float* src[NMAT]; int ldw[NMAT]; };
struct OutP { float* p[8]; };
struct InP { const float* p[8]; };

__device__ inline unsigned short f2bf(float x) {
    union { float f; unsigned u; } v; v.f = x;
    unsigned r = v.u + 0x7FFFu + ((v.u >> 16) & 1u);
    return (unsigned short)(r >> 16);
}
__device__ inline float bf2f(unsigned short h) {
    union { unsigned u; float f; } v; v.u = ((unsigned)h) << 16;
    return v.f;
}
__device__ inline void cvt8(const float4& v0, const float4& v1, bf16x8& h,
                            bf16x8& l) {
    float f[8] = {v0.x, v0.y, v0.z, v0.w, v1.x, v1.y, v1.z, v1.w};
#pragma unroll
    for (int j = 0; j < 8; ++j) {
        unsigned short hh = f2bf(f[j]);
        h[j] = (short)hh;
        l[j] = (short)f2bf(f[j] - bf2f(hh));
    }
}
__device__ inline f32x4 MF(bf16x8 a, bf16x8 b, f32x4 c) {
    return __builtin_amdgcn_mfma_f32_16x16x32_bf16(a, b, c, 0, 0, 0);
}

// ---------------------------------------------------------------------------
// Streaming batched MFMA GEMM, no LDS. Wave = 16 rows x 128 cols.
// All A loads issued upfront (one latency round); A reused across nw mats.
// out_w[n][o] = act( A[n][:] . W_w[o][:] (+bias_w) (+addin) )
// In-place safe: A rows fully loaded before any store; wave spans same rows.
// ---------------------------------------------------------------------------
template <int BIAS, int RELU, int ADDIN>
__global__ __launch_bounds__(256, 4) void gemm_multi_kernel(
    const float* __restrict__ A, const unsigned short* __restrict__ Wc,
    int nw, OutP outs, const float* __restrict__ bias, int bias_stride,
    const float* __restrict__ addin, int N) {
    int t = threadIdx.x, lane = t & 63;
    int wave = t >> 6;
    int fr = lane & 15, fq = lane >> 4;
    int rbase = blockIdx.x * 64 + wave * 16;
    int arow = rbase + fr;
    const float* ap = A + (size_t)arow * D;
    bool ok = arow < N;

    // upfront A loads: 8 independent float4 (one latency round)
    float4 araw[8];
#pragma unroll
    for (int kc = 0; kc < 4; ++kc) {
        float4 z = {0.f, 0.f, 0.f, 0.f};
        araw[2 * kc] = ok ? *(const float4*)(ap + kc * 32 + fq * 8) : z;
        araw[2 * kc + 1] = ok ? *(const float4*)(ap + kc * 32 + fq * 8 + 4) : z;
    }
    bf16x8 ah[4], al[4];
#pragma unroll
    for (int kc = 0; kc < 4; ++kc)
        cvt8(araw[2 * kc], araw[2 * kc + 1], ah[kc], al[kc]);

    for (int w = 0; w < nw; ++w) {
        const unsigned short* wm = Wc + (size_t)w * MATSZ;
        f32x4 acc[8];
#pragma unroll
        for (int n = 0; n < 8; ++n) acc[n] = (f32x4){0.f, 0.f, 0.f, 0.f};
#pragma unroll
        for (int kc = 0; kc < 4; ++kc) {
            int ko = kc * 32 + fq * 8;
#pragma unroll
            for (int n = 0; n < 8; ++n) {
                const unsigned short* wp = wm + (size_t)(n * 16 + fr) * D + ko;
                bf16x8 wh = *(const bf16x8*)wp;
                bf16x8 wl = *(const bf16x8*)(wp + 16384);
                acc[n] = MF(ah[kc], wh, acc[n]);
                acc[n] = MF(ah[kc], wl, acc[n]);
                acc[n] = MF(al[kc], wh, acc[n]);
            }
        }
        // epilogue: C row = rbase + fq*4 + j, col = n*16 + fr
        float* op = outs.p[w];
        const float* bp = BIAS ? bias + (size_t)w * bias_stride : nullptr;
#pragma unroll
        for (int j = 0; j < 4; ++j) {
            int row = rbase + fq * 4 + j;
            if (row < N) {
#pragma unroll
                for (int n = 0; n < 8; ++n) {
                    int c = n * 16 + fr;
                    float r = acc[n][j];
                    if (BIAS) r += bp[c];
                    if (ADDIN) r += addin[(size_t)row * D + c];
                    if (RELU) r = fmaxf(r, 0.f);
                    op[(size_t)row * D + c] = r;
                }
            }
        }
    }
}

static inline void launch_gemm(const float* A, const unsigned short* Wc, int nw,
                               OutP outs, const float* bias, int bstride,
                               const float* addin, bool relu, int N,
                               hipStream_t s) {
    dim3 grid((N + 63) / 64), blk(256);
    bool B = bias != nullptr, AD = addin != nullptr;
    if (!B && !relu && !AD)
        gemm_multi_kernel<0, 0, 0><<<grid, blk, 0, s>>>(A, Wc, nw, outs, bias, bstride, addin, N);
    else if (B && !relu && !AD)
        gemm_multi_kernel<1, 0, 0><<<grid, blk, 0, s>>>(A, Wc, nw, outs, bias, bstride, addin, N);
    else if (B && relu && !AD)
        gemm_multi_kernel<1, 1, 0><<<grid, blk, 0, s>>>(A, Wc, nw, outs, bias, bstride, addin, N);
    else if (B && relu && AD)
        gemm_multi_kernel<1, 1, 1><<<grid, blk, 0, s>>>(A, Wc, nw, outs, bias, bstride, addin, N);
    else if (!B && relu && AD)
        gemm_multi_kernel<0, 1, 1><<<grid, blk, 0, s>>>(A, Wc, nw, outs, bias, bstride, addin, N);
    else if (!B && !relu && AD)
        gemm_multi_kernel<0, 0, 1><<<grid, blk, 0, s>>>(A, Wc, nw, outs, bias, bstride, addin, N);
    else if (B && !relu && AD)
        gemm_multi_kernel<1, 0, 1><<<grid, blk, 0, s>>>(A, Wc, nw, outs, bias, bstride, addin, N);
    else
        gemm_multi_kernel<0, 1, 0><<<grid, blk, 0, s>>>(A, Wc, nw, outs, bias, bstride, addin, N);
}

// ---------------------------------------------------------------------------
// h = relu(x @ W1.T + b1) for the two K=2 input MLPs (fused)  [R2-proven]
// ---------------------------------------------------------------------------
__global__ void input_hidden_kernel(const float* __restrict__ ctrs,
                                    const float* __restrict__ feats,
                                    const float* __restrict__ inW1,
                                    const float* __restrict__ inb1,
                                    const float* __restrict__ segW1,
                                    const float* __restrict__ segb1,
                                    float* __restrict__ h_in,
                                    float* __restrict__ h_seg, int N) {
    int gid = blockIdx.x * blockDim.x + threadIdx.x;
    int n = gid >> 5;
    int c = gid & 31;
    if (n >= N) return;
    float x0 = ctrs[2 * n], x1 = ctrs[2 * n + 1];
    float y0 = feats[2 * n], y1 = feats[2 * n + 1];
    int o0 = c * 4;
    float hi[4], hs[4];
#pragma unroll
    for (int j = 0; j < 4; ++j) {
        int o = o0 + j;
        float a = fmaf(x0, inW1[2 * o], fmaf(x1, inW1[2 * o + 1], inb1[o]));
        hi[j] = fmaxf(a, 0.f);
        float b = fmaf(y0, segW1[2 * o], fmaf(y1, segW1[2 * o + 1], segb1[o]));
        hs[j] = fmaxf(b, 0.f);
    }
    *(float4*)&h_in[(size_t)n * D + o0] = make_float4(hi[0], hi[1], hi[2], hi[3]);
    *(float4*)&h_seg[(size_t)n * D + o0] = make_float4(hs[0], hs[1], hs[2], hs[3]);
}

// ---------------------------------------------------------------------------
// Multi-type CSR gather [R4-proven]: one wave per node; temp read+written once
// per group. NORM: fuse GroupNorm(1,D)+affine+relu on the last group.
// ---------------------------------------------------------------------------
template <int NORM>
__global__ __launch_bounds__(256) void csr_gather_multi_kernel(
    InP Y, const int* __restrict__ rowptr, const int* __restrict__ col,
    float* temp, int N, int nt, int E, const float* __restrict__ g,
    const float* __restrict__ b) {
    int wid = (int)((blockIdx.x * (size_t)blockDim.x + threadIdx.x) >> 6);
    int lane = threadIdx.x & 63;
    if (wid >= N) return;
    size_t ro = (size_t)wid * D + lane * 2;
    float2 acc = *(float2*)&temp[ro];
    for (int j = 0; j < nt; ++j) {
        const int* rp = rowptr + (size_t)j * (N + 1);
        int beg = rp[wid];
        int end = rp[wid + 1];
        const float* Yj = Y.p[j];
        const int* cj = col + (size_t)j * E;
        for (int k = beg; k < end; ++k) {
            int v = cj[k];
            float2 y = *(const float2*)&Yj[(size_t)v * D + lane * 2];
            acc.x += y.x;
            acc.y += y.y;
        }
    }
    if (NORM) {
        float s = acc.x + acc.y;
        float sq = acc.x * acc.x + acc.y * acc.y;
#pragma unroll
        for (int off = 32; off; off >>= 1) {
            s += __shfl_xor(s, off);
            sq += __shfl_xor(sq, off);
        }
        float mu = s * (1.f / 128.f);
        float var = sq * (1.f / 128.f) - mu * mu;
        float rs = rsqrtf(var + 1e-5f);
        acc.x = fmaxf(fmaf((acc.x - mu) * rs, g[lane * 2], b[lane * 2]), 0.f);
        acc.y = fmaxf(fmaf((acc.y - mu) * rs, g[lane * 2 + 1], b[lane * 2 + 1]), 0.f);
    }
    *(float2*)&temp[ro] = acc;
}

// ---------------------------------------------------------------------------
__global__ void gather_meta_kernel(const int* __restrict__ mark,
                                   const float* __restrict__ embed, float* out,
                                   int N) {
    int gid = blockIdx.x * blockDim.x + threadIdx.x;
    int n = gid >> 5;
    int c = gid & 31;
    if (n >= N) return;
    *(float4*)&out[(size_t)n * D + c * 4] =
        *(const float4*)&embed[(size_t)mark[n] * D + c * 4];
}

// ---------------------------------------------------------------------------
// weight pre-conversion (proven)
// ---------------------------------------------------------------------------
__global__ __launch_bounds__(256) void wcvt_kernel(CvtTab tab,
                                                   unsigned short* dst) {
    int bid = blockIdx.x;
    int mat = bid >> 4;
    if (mat >= NMAT) return;
    int e = (bid & 15) * 1024 + threadIdx.x * 4;
    int o = e >> 7, k = e & 127;
    const float* s = tab.src[mat];
    int ldw = tab.ldw[mat];
    float4 v = *(const float4*)&s[(size_t)o * ldw + k];
    ushort4 h, l;
    h.x = f2bf(v.x); l.x = f2bf(v.x - bf2f(h.x));
    h.y = f2bf(v.y); l.y = f2bf(v.y - bf2f(h.y));
    h.z = f2bf(v.z); l.z = f2bf(v.z - bf2f(h.z));
    h.w = f2bf(v.w); l.w = f2bf(v.w - bf2f(h.w));
    *(ushort4*)&dst[(size_t)mat * MATSZ + e] = h;
    *(ushort4*)&dst[(size_t)mat * MATSZ + 16384 + e] = l;
}

// ---------------------------------------------------------------------------
// CSR build (proven; no rowid)
// ---------------------------------------------------------------------------
__global__ void csr_hist_kernel(const int* __restrict__ edge_u, int* deg,
                                int N, int E) {
    int gid = blockIdx.x * blockDim.x + threadIdx.x;
    if (gid >= NT * E) return;
    int t = gid / E;
    int u = edge_u[gid];
    atomicAdd(&deg[(size_t)t * N + u], 1);
}

__global__ __launch_bounds__(256) void csr_chunksum_kernel(
    const int* __restrict__ deg, int* csum, int N, int nch) {
    int b = blockIdx.x;
    int t = b / nch, ch = b % nch;
    int tid = threadIdx.x;
    const int* dg = deg + (size_t)t * N;
    int base = ch * SCH + tid * 4;
    int s = 0;
#pragma unroll
    for (int j = 0; j < 4; ++j) {
        int idx = base + j;
        if (idx < N) s += dg[idx];
    }
#pragma unroll
    for (int off = 32; off; off >>= 1) s += __shfl_down(s, off);
    __shared__ int wsum[4];
    if ((tid & 63) == 0) wsum[tid >> 6] = s;
    __syncthreads();
    if (tid == 0) csum[b] = wsum[0] + wsum[1] + wsum[2] + wsum[3];
}

__global__ void csr_chunkscan_kernel(int* csum, int* rowptr, int N, int nch) {
    int t = threadIdx.x;
    if (t >= NT) return;
    int run = 0;
    for (int i = 0; i < nch; ++i) {
        int v = csum[t * nch + i];
        csum[t * nch + i] = run;
        run += v;
    }
    rowptr[(size_t)t * (N + 1) + N] = run;
}

__global__ __launch_bounds__(256) void csr_blockscan_kernel(
    const int* __restrict__ deg, const int* __restrict__ csum, int* rowptr,
    int* cur, int N, int nch) {
    int b = blockIdx.x;
    int t = b / nch, ch = b % nch;
    int tid = threadIdx.x;
    const int* dg = deg + (size_t)t * N;
    int base = ch * SCH + tid * 4;
    int d[4];
    int s = 0;
#pragma unroll
    for (int j = 0; j < 4; ++j) {
        int idx = base + j;
        d[j] = (idx < N) ? dg[idx] : 0;
        s += d[j];
    }
    __shared__ int ps[256];
    ps[tid] = s;
    __syncthreads();
    for (int off = 1; off < 256; off <<= 1) {
        int v = (tid >= off) ? ps[tid - off] : 0;
        __syncthreads();
        ps[tid] += v;
        __syncthreads();
    }
    int excl = (tid ? ps[tid - 1] : 0) + csum[b];
    size_t rb = (size_t)t * (N + 1);
#pragma unroll
    for (int j = 0; j < 4; ++j) {
        int idx = base + j;
        if (idx < N) {
            rowptr[rb + idx] = excl;
            cur[rb + idx] = excl;
            excl += d[j];
        }
    }
}

__global__ void csr_fill_kernel(const int* __restrict__ edge_u,
                                const int* __restrict__ edge_v, int* cur,
                                int* col, int N, int E) {
    int gid = blockIdx.x * blockDim.x + threadIdx.x;
    if (gid >= NT * E) return;
    int t = gid / E;
    int u = edge_u[gid];
    int v = edge_v[gid];
    int pos = atomicAdd(&cur[(size_t)t * (N + 1) + u], 1);
    col[(size_t)t * E + pos] = v;
}

// ---------------------------------------------------------------------------
extern "C" void kernel_launch(void* const* d_in, const int* in_sizes, int n_in,
                              void* d_out, int out_size, void* d_ws,
                              size_t ws_size, hipStream_t stream) {
    const float* ctrs = (const float*)d_in[0];
    const float* feats = (const float*)d_in[1];
    const float* in_W1 = (const float*)d_in[2];
    const float* in_b1 = (const float*)d_in[3];
    const float* in_W2 = (const float*)d_in[4];
    const float* in_b2 = (const float*)d_in[5];
    const float* seg_W1 = (const float*)d_in[6];
    const float* seg_b1 = (const float*)d_in[7];
    const float* seg_W2 = (const float*)d_in[8];
    const float* seg_b2 = (const float*)d_in[9];
    const float* embed = (const float*)d_in[10];
    const float* meta_W1 = (const float*)d_in[11];
    const float* meta_b1 = (const float*)d_in[12];
    const float* meta_W2 = (const float*)d_in[13];
    const float* meta_b2 = (const float*)d_in[14];
    const float* ctr_W = (const float*)d_in[15];
    const float* edge_W = (const float*)d_in[16];
    const float* norm_g = (const float*)d_in[17];
    const float* norm_b = (const float*)d_in[18];
    const float* ctr2_W1 = (const float*)d_in[19];
    const float* ctr2_b1 = (const float*)d_in[20];
    const float* ctr2_W2 = (const float*)d_in[21];
    const float* ctr2_b2 = (const float*)d_in[22];
    const int* mark_type = (const int*)d_in[23];
    const int* edge_u = (const int*)d_in[24];
    const int* edge_v = (const int*)d_in[25];

    const int N = in_sizes[0] / 2;
    const int E = in_sizes[24] / NT;
    const size_t ND = (size_t)N * D;
    const int nch = (N + SCH - 1) / SCH;

    // ws layout: [Wcvt 3.7MB | F 77MB | temp 77MB | rowptr 5.7 | col 5.7 | Yslots...]
    unsigned short* Wcvt = (unsigned short*)d_ws;
    size_t wcB = ((size_t)NMAT * MATSZ * sizeof(unsigned short) + 255) & ~(size_t)255;
    float* F = (float*)((char*)d_ws + wcB);
    float* temp = F + ND;
    int* rowptr = (int*)(temp + ND);
    int* col = rowptr + (size_t)NT * (N + 1);
    size_t base = (size_t)((char*)(col + (size_t)NT * E) - (char*)d_ws);
    base = (base + 255) & ~(size_t)255;
    float* Yws = (float*)((char*)d_ws + base);
    int extra = 0;
    if (ws_size > base + 256)
        extra = (int)((ws_size - base - 256) / (ND * sizeof(float)));
    int slots = 1 + (extra > 4 ? 4 : extra);  // slot0 = d_out (always free mid-run)

    // weight conversion table
    CvtTab tab;
    tab.src[0] = in_W2;  tab.ldw[0] = D;
    tab.src[1] = seg_W2; tab.ldw[1] = D;
    for (int i = 0; i < NL; ++i) { tab.src[2 + i] = ctr2_W1 + (size_t)i * D * D; tab.ldw[2 + i] = D; }
    for (int i = 0; i < NL; ++i) { tab.src[6 + i] = ctr2_W2 + (size_t)i * D * D; tab.ldw[6 + i] = D; }
    for (int i = 0; i < NL; ++i) {
        for (int t = 0; t < NT; ++t) {
            int id = 10 + i * 11 + t;
            tab.src[id] = edge_W + ((size_t)i * NT + t) * D * D;
            tab.ldw[id] = D;
        }
        tab.src[10 + i * 11 + 10] = ctr_W + (size_t)i * D * D;
        tab.ldw[10 + i * 11 + 10] = D;
    }
    tab.src[54] = meta_W1;     tab.ldw[54] = 2 * D;
    tab.src[55] = meta_W1 + D; tab.ldw[55] = 2 * D;
    tab.src[56] = meta_W2;     tab.ldw[56] = D;
    wcvt_kernel<<<NMAT * 16, 256, 0, stream>>>(tab, Wcvt);

    dim3 blk(256);
    dim3 gTE(((size_t)NT * E + 255) / 256);
    dim3 g32((N * 32 + 255) / 256);
    dim3 g64(((size_t)N * 64 + 255) / 256);

    // CSR build (d_out is scratch here, freed after)
    {
        int* deg = (int*)d_out;
        int* cur = deg + (size_t)NT * N;
        int* csum = cur + (size_t)NT * (N + 1);
        hipMemsetAsync(deg, 0, (size_t)NT * N * sizeof(int), stream);
        csr_hist_kernel<<<gTE, blk, 0, stream>>>(edge_u, deg, N, E);
        csr_chunksum_kernel<<<NT * nch, blk, 0, stream>>>(deg, csum, N, nch);
        csr_chunkscan_kernel<<<1, 64, 0, stream>>>(csum, rowptr, N, nch);
        csr_blockscan_kernel<<<NT * nch, blk, 0, stream>>>(deg, csum, rowptr, cur, N, nch);
        csr_fill_kernel<<<gTE, blk, 0, stream>>>(edge_u, edge_v, cur, col, N, E);
    }

    float* slotp[5];
    slotp[0] = (float*)d_out;
    for (int i = 1; i < slots; ++i) slotp[i] = Yws + (size_t)(i - 1) * ND;

    // ---- input stage: F = relu(h1@W2in + b + h2@W2seg + b) ----
    {
        // h1 -> F (in-place GEMM safe), h2 -> d_out
        input_hidden_kernel<<<g32, blk, 0, stream>>>(ctrs, feats, in_W1, in_b1,
                                                     seg_W1, seg_b1, F,
                                                     (float*)d_out, N);
        OutP o{}; o.p[0] = F;
        launch_gemm(F, Wcvt + (size_t)0 * MATSZ, 1, o, in_b2, 0, nullptr, false, N, stream);
        launch_gemm((float*)d_out, Wcvt + (size_t)1 * MATSZ, 1, o, seg_b2, 0, F, true, N, stream);
    }

    // ---- fuse layers ----
    for (int i = 0; i < NL; ++i) {
        const unsigned short* WL = Wcvt + (size_t)(10 + i * 11) * MATSZ;
        // ctr term -> temp
        OutP oc{}; oc.p[0] = temp;
        launch_gemm(F, WL + (size_t)10 * MATSZ, 1, oc, nullptr, 0, nullptr, false, N, stream);
        // edge groups
        for (int g0 = 0; g0 < NT; g0 += slots) {
            int cnt = (NT - g0 < slots) ? (NT - g0) : slots;
            OutP oy{};
            InP iy{};
            for (int j = 0; j < cnt; ++j) { oy.p[j] = slotp[j]; iy.p[j] = slotp[j]; }
            launch_gemm(F, WL + (size_t)g0 * MATSZ, cnt, oy, nullptr, 0, nullptr, false, N, stream);
            bool last = (g0 + cnt == NT);
            if (last)
                csr_gather_multi_kernel<1><<<g64, blk, 0, stream>>>(
                    iy, rowptr + (size_t)g0 * (N + 1), col + (size_t)g0 * E,
                    temp, N, cnt, E, norm_g + (size_t)i * D,
                    norm_b + (size_t)i * D);
            else
                csr_gather_multi_kernel<0><<<g64, blk, 0, stream>>>(
                    iy, rowptr + (size_t)g0 * (N + 1), col + (size_t)g0 * E,
                    temp, N, cnt, E, nullptr, nullptr);
        }
        // MLP1: temp -> H (d_out), MLP2: H -> F (in-place residual)
        OutP oh{}; oh.p[0] = (float*)d_out;
        launch_gemm(temp, Wcvt + (size_t)(2 + i) * MATSZ, 1, oh,
                    ctr2_b1 + (size_t)i * D, 0, nullptr, true, N, stream);
        OutP of{}; of.p[0] = F;
        launch_gemm((float*)d_out, Wcvt + (size_t)(6 + i) * MATSZ, 1, of,
                    ctr2_b2 + (size_t)i * D, 0, F, true, N, stream);
    }

    // ---- meta stage ----
    {
        // T = F@W54 + b1 -> temp
        OutP ot{}; ot.p[0] = temp;
        launch_gemm(F, Wcvt + (size_t)54 * MATSZ, 1, ot, meta_b1, 0, nullptr, false, N, stream);
        // M -> d_out
        gather_meta_kernel<<<g32, blk, 0, stream>>>(mark_type, embed, (float*)d_out, N);
        // H = relu(M@W55 + T) -> temp (in-place addin)
        launch_gemm((float*)d_out, Wcvt + (size_t)55 * MATSZ, 1, ot, nullptr, 0, temp, true, N, stream);
        // out = H@W56 + b2 -> d_out
        OutP oo{}; oo.p[0] = (float*)d_out;
        launch_gemm(temp, Wcvt + (size_t)56 * MATSZ, 1, oo, meta_b2, 0, nullptr, false, N, stream);
    }
}

// Round 11
// 4958.826 us; speedup vs baseline: 1.4420x; 1.4420x over previous
//
#include <hip/hip_runtime.h>

#define D 128
#define NT 10    // edge types
#define NL 4     // layers
#define SCH 1024 // nodes per scan chunk
#define NMAT 57
#define MATSZ 32768  // shorts per converted matrix (hi 16384 + lo 16384)

typedef __attribute__((ext_vector_type(8))) short bf16x8;
typedef __attribute__((ext_vector_type(4))) float f32x4;

struct CvtTab { const float* src[NMAT]; int ldw[NMAT]; };
struct OutP { float* p[8]; };
struct InP { const float* p[8]; };

__device__ inline unsigned short f2bf(float x) {
    union { float f; unsigned u; } v; v.f = x;
    unsigned r = v.u + 0x7FFFu + ((v.u >> 16) & 1u);
    return (unsigned short)(r >> 16);
}
__device__ inline float bf2f(unsigned short h) {
    union { unsigned u; float f; } v; v.u = ((unsigned)h) << 16;
    return v.f;
}
__device__ inline void cvt8(const float4& v0, const float4& v1, bf16x8& h,
                            bf16x8& l) {
    float f[8] = {v0.x, v0.y, v0.z, v0.w, v1.x, v1.y, v1.z, v1.w};
#pragma unroll
    for (int j = 0; j < 8; ++j) {
        unsigned short hh = f2bf(f[j]);
        h[j] = (short)hh;
        l[j] = (short)f2bf(f[j] - bf2f(hh));
    }
}
__device__ inline f32x4 MF(bf16x8 a, bf16x8 b, f32x4 c) {
    return __builtin_amdgcn_mfma_f32_16x16x32_bf16(a, b, c, 0, 0, 0);
}

// ---------------------------------------------------------------------------
// Streaming batched MFMA GEMM, no LDS. Wave = 16 rows x 128 cols.
// W is PRE-SWIZZLED in fragment order: chunk ((kc*8+n)*64 + lane) of 8 bf16,
// so each wave W-load is contiguous (full L2-line utilization; the R10
// pattern wasted 4x on 16B-per-256B-stride reads -> L2-BW-bound at 26 TB/s).
// ---------------------------------------------------------------------------
template <int BIAS, int RELU, int ADDIN>
__global__ __launch_bounds__(256, 4) void gemm_multi_kernel(
    const float* __restrict__ A, const unsigned short* __restrict__ Wc,
    int nw, OutP outs, const float* __restrict__ bias, int bias_stride,
    const float* __restrict__ addin, int N) {
    int t = threadIdx.x, lane = t & 63;
    int wave = t >> 6;
    int fr = lane & 15, fq = lane >> 4;
    int rbase = blockIdx.x * 64 + wave * 16;
    int arow = rbase + fr;
    const float* ap = A + (size_t)arow * D;
    bool ok = arow < N;

    // upfront A loads: 8 independent float4 (one latency round), reused over nw
    float4 araw[8];
#pragma unroll
    for (int kc = 0; kc < 4; ++kc) {
        float4 z = {0.f, 0.f, 0.f, 0.f};
        araw[2 * kc] = ok ? *(const float4*)(ap + kc * 32 + fq * 8) : z;
        araw[2 * kc + 1] = ok ? *(const float4*)(ap + kc * 32 + fq * 8 + 4) : z;
    }
    bf16x8 ah[4], al[4];
#pragma unroll
    for (int kc = 0; kc < 4; ++kc)
        cvt8(araw[2 * kc], araw[2 * kc + 1], ah[kc], al[kc]);

    for (int w = 0; w < nw; ++w) {
        const unsigned short* wm = Wc + (size_t)w * MATSZ;
        f32x4 acc[8];
#pragma unroll
        for (int n = 0; n < 8; ++n) acc[n] = (f32x4){0.f, 0.f, 0.f, 0.f};
#pragma unroll
        for (int kc = 0; kc < 4; ++kc) {
#pragma unroll
            for (int n = 0; n < 8; ++n) {
                const unsigned short* wk =
                    wm + (size_t)(((kc * 8 + n) * 64 + lane) * 8);
                bf16x8 wh = *(const bf16x8*)wk;
                bf16x8 wl = *(const bf16x8*)(wk + 16384);
                acc[n] = MF(ah[kc], wh, acc[n]);
                acc[n] = MF(ah[kc], wl, acc[n]);
                acc[n] = MF(al[kc], wh, acc[n]);
            }
        }
        // epilogue: C row = rbase + fq*4 + j, col = n*16 + fr
        float* op = outs.p[w];
        const float* bp = BIAS ? bias + (size_t)w * bias_stride : nullptr;
#pragma unroll
        for (int j = 0; j < 4; ++j) {
            int row = rbase + fq * 4 + j;
            if (row < N) {
#pragma unroll
                for (int n = 0; n < 8; ++n) {
                    int c = n * 16 + fr;
                    float r = acc[n][j];
                    if (BIAS) r += bp[c];
                    if (ADDIN) r += addin[(size_t)row * D + c];
                    if (RELU) r = fmaxf(r, 0.f);
                    op[(size_t)row * D + c] = r;
                }
            }
        }
    }
}

static inline void launch_gemm(const float* A, const unsigned short* Wc, int nw,
                               OutP outs, const float* bias, int bstride,
                               const float* addin, bool relu, int N,
                               hipStream_t s) {
    dim3 grid((N + 63) / 64), blk(256);
    bool B = bias != nullptr, AD = addin != nullptr;
    if (!B && !relu && !AD)
        gemm_multi_kernel<0, 0, 0><<<grid, blk, 0, s>>>(A, Wc, nw, outs, bias, bstride, addin, N);
    else if (B && !relu && !AD)
        gemm_multi_kernel<1, 0, 0><<<grid, blk, 0, s>>>(A, Wc, nw, outs, bias, bstride, addin, N);
    else if (B && relu && !AD)
        gemm_multi_kernel<1, 1, 0><<<grid, blk, 0, s>>>(A, Wc, nw, outs, bias, bstride, addin, N);
    else if (B && relu && AD)
        gemm_multi_kernel<1, 1, 1><<<grid, blk, 0, s>>>(A, Wc, nw, outs, bias, bstride, addin, N);
    else if (!B && relu && AD)
        gemm_multi_kernel<0, 1, 1><<<grid, blk, 0, s>>>(A, Wc, nw, outs, bias, bstride, addin, N);
    else if (!B && !relu && AD)
        gemm_multi_kernel<0, 0, 1><<<grid, blk, 0, s>>>(A, Wc, nw, outs, bias, bstride, addin, N);
    else if (B && !relu && AD)
        gemm_multi_kernel<1, 0, 1><<<grid, blk, 0, s>>>(A, Wc, nw, outs, bias, bstride, addin, N);
    else
        gemm_multi_kernel<0, 1, 0><<<grid, blk, 0, s>>>(A, Wc, nw, outs, bias, bstride, addin, N);
}

// ---------------------------------------------------------------------------
// h = relu(x @ W1.T + b1) for the two K=2 input MLPs (fused)  [R2-proven]
// ---------------------------------------------------------------------------
__global__ void input_hidden_kernel(const float* __restrict__ ctrs,
                                    const float* __restrict__ feats,
                                    const float* __restrict__ inW1,
                                    const float* __restrict__ inb1,
                                    const float* __restrict__ segW1,
                                    const float* __restrict__ segb1,
                                    float* __restrict__ h_in,
                                    float* __restrict__ h_seg, int N) {
    int gid = blockIdx.x * blockDim.x + threadIdx.x;
    int n = gid >> 5;
    int c = gid & 31;
    if (n >= N) return;
    float x0 = ctrs[2 * n], x1 = ctrs[2 * n + 1];
    float y0 = feats[2 * n], y1 = feats[2 * n + 1];
    int o0 = c * 4;
    float hi[4], hs[4];
#pragma unroll
    for (int j = 0; j < 4; ++j) {
        int o = o0 + j;
        float a = fmaf(x0, inW1[2 * o], fmaf(x1, inW1[2 * o + 1], inb1[o]));
        hi[j] = fmaxf(a, 0.f);
        float b = fmaf(y0, segW1[2 * o], fmaf(y1, segW1[2 * o + 1], segb1[o]));
        hs[j] = fmaxf(b, 0.f);
    }
    *(float4*)&h_in[(size_t)n * D + o0] = make_float4(hi[0], hi[1], hi[2], hi[3]);
    *(float4*)&h_seg[(size_t)n * D + o0] = make_float4(hs[0], hs[1], hs[2], hs[3]);
}

// ---------------------------------------------------------------------------
// Multi-type CSR gather [R4-proven]: one wave per node; temp read+written once
// per group. NORM: fuse GroupNorm(1,D)+affine+relu on the last group.
// ---------------------------------------------------------------------------
template <int NORM>
__global__ __launch_bounds__(256) void csr_gather_multi_kernel(
    InP Y, const int* __restrict__ rowptr, const int* __restrict__ col,
    float* temp, int N, int nt, int E, const float* __restrict__ g,
    const float* __restrict__ b) {
    int wid = (int)((blockIdx.x * (size_t)blockDim.x + threadIdx.x) >> 6);
    int lane = threadIdx.x & 63;
    if (wid >= N) return;
    size_t ro = (size_t)wid * D + lane * 2;
    float2 acc = *(float2*)&temp[ro];
    for (int j = 0; j < nt; ++j) {
        const int* rp = rowptr + (size_t)j * (N + 1);
        int beg = rp[wid];
        int end = rp[wid + 1];
        const float* Yj = Y.p[j];
        const int* cj = col + (size_t)j * E;
        for (int k = beg; k < end; ++k) {
            int v = cj[k];
            float2 y = *(const float2*)&Yj[(size_t)v * D + lane * 2];
            acc.x += y.x;
            acc.y += y.y;
        }
    }
    if (NORM) {
        float s = acc.x + acc.y;
        float sq = acc.x * acc.x + acc.y * acc.y;
#pragma unroll
        for (int off = 32; off; off >>= 1) {
            s += __shfl_xor(s, off);
            sq += __shfl_xor(sq, off);
        }
        float mu = s * (1.f / 128.f);
        float var = sq * (1.f / 128.f) - mu * mu;
        float rs = rsqrtf(var + 1e-5f);
        acc.x = fmaxf(fmaf((acc.x - mu) * rs, g[lane * 2], b[lane * 2]), 0.f);
        acc.y = fmaxf(fmaf((acc.y - mu) * rs, g[lane * 2 + 1], b[lane * 2 + 1]), 0.f);
    }
    *(float2*)&temp[ro] = acc;
}

// ---------------------------------------------------------------------------
__global__ void gather_meta_kernel(const int* __restrict__ mark,
                                   const float* __restrict__ embed, float* out,
                                   int N) {
    int gid = blockIdx.x * blockDim.x + threadIdx.x;
    int n = gid >> 5;
    int c = gid & 31;
    if (n >= N) return;
    *(float4*)&out[(size_t)n * D + c * 4] =
        *(const float4*)&embed[(size_t)mark[n] * D + c * 4];
}

// ---------------------------------------------------------------------------
// weight pre-conversion into SWIZZLED fragment order:
// chunk c in [0,2048): kc=c>>9, n=(c>>6)&7, lane=c&63 (fq=lane>>4, fr=lane&15)
// src:  W[o = n*16+fr][k0 = kc*32+fq*8 .. +7]
// dst:  hi plane at c*8, lo plane at 16384 + c*8
// ---------------------------------------------------------------------------
__global__ __launch_bounds__(256) void wcvt_kernel(CvtTab tab,
                                                   unsigned short* dst) {
    int bid = blockIdx.x;
    int mat = bid >> 3;
    if (mat >= NMAT) return;
    int c = (bid & 7) * 256 + threadIdx.x;
    int kc = c >> 9, n = (c >> 6) & 7, lane = c & 63;
    int fq = lane >> 4, fr = lane & 15;
    int o = n * 16 + fr;
    int k0 = kc * 32 + fq * 8;
    const float* s = tab.src[mat];
    int ldw = tab.ldw[mat];
    float4 v0 = *(const float4*)&s[(size_t)o * ldw + k0];
    float4 v1 = *(const float4*)&s[(size_t)o * ldw + k0 + 4];
    float f[8] = {v0.x, v0.y, v0.z, v0.w, v1.x, v1.y, v1.z, v1.w};
    unsigned short h[8], l[8];
#pragma unroll
    for (int j = 0; j < 8; ++j) {
        h[j] = f2bf(f[j]);
        l[j] = f2bf(f[j] - bf2f(h[j]));
    }
    unsigned short* dh = dst + (size_t)mat * MATSZ + (size_t)c * 8;
    unsigned short* dl = dh + 16384;
#pragma unroll
    for (int j = 0; j < 8; ++j) { dh[j] = h[j]; dl[j] = l[j]; }
}

// ---------------------------------------------------------------------------
// CSR build (proven)
// ---------------------------------------------------------------------------
__global__ void csr_hist_kernel(const int* __restrict__ edge_u, int* deg,
                                int N, int E) {
    int gid = blockIdx.x * blockDim.x + threadIdx.x;
    if (gid >= NT * E) return;
    int t = gid / E;
    int u = edge_u[gid];
    atomicAdd(&deg[(size_t)t * N + u], 1);
}

__global__ __launch_bounds__(256) void csr_chunksum_kernel(
    const int* __restrict__ deg, int* csum, int N, int nch) {
    int b = blockIdx.x;
    int t = b / nch, ch = b % nch;
    int tid = threadIdx.x;
    const int* dg = deg + (size_t)t * N;
    int base = ch * SCH + tid * 4;
    int s = 0;
#pragma unroll
    for (int j = 0; j < 4; ++j) {
        int idx = base + j;
        if (idx < N) s += dg[idx];
    }
#pragma unroll
    for (int off = 32; off; off >>= 1) s += __shfl_down(s, off);
    __shared__ int wsum[4];
    if ((tid & 63) == 0) wsum[tid >> 6] = s;
    __syncthreads();
    if (tid == 0) csum[b] = wsum[0] + wsum[1] + wsum[2] + wsum[3];
}

__global__ void csr_chunkscan_kernel(int* csum, int* rowptr, int N, int nch) {
    int t = threadIdx.x;
    if (t >= NT) return;
    int run = 0;
    for (int i = 0; i < nch; ++i) {
        int v = csum[t * nch + i];
        csum[t * nch + i] = run;
        run += v;
    }
    rowptr[(size_t)t * (N + 1) + N] = run;
}

__global__ __launch_bounds__(256) void csr_blockscan_kernel(
    const int* __restrict__ deg, const int* __restrict__ csum, int* rowptr,
    int* cur, int N, int nch) {
    int b = blockIdx.x;
    int t = b / nch, ch = b % nch;
    int tid = threadIdx.x;
    const int* dg = deg + (size_t)t * N;
    int base = ch * SCH + tid * 4;
    int d[4];
    int s = 0;
#pragma unroll
    for (int j = 0; j < 4; ++j) {
        int idx = base + j;
        d[j] = (idx < N) ? dg[idx] : 0;
        s += d[j];
    }
    __shared__ int ps[256];
    ps[tid] = s;
    __syncthreads();
    for (int off = 1; off < 256; off <<= 1) {
        int v = (tid >= off) ? ps[tid - off] : 0;
        __syncthreads();
        ps[tid] += v;
        __syncthreads();
    }
    int excl = (tid ? ps[tid - 1] : 0) + csum[b];
    size_t rb = (size_t)t * (N + 1);
#pragma unroll
    for (int j = 0; j < 4; ++j) {
        int idx = base + j;
        if (idx < N) {
            rowptr[rb + idx] = excl;
            cur[rb + idx] = excl;
            excl += d[j];
        }
    }
}

__global__ void csr_fill_kernel(const int* __restrict__ edge_u,
                                const int* __restrict__ edge_v, int* cur,
                                int* col, int N, int E) {
    int gid = blockIdx.x * blockDim.x + threadIdx.x;
    if (gid >= NT * E) return;
    int t = gid / E;
    int u = edge_u[gid];
    int v = edge_v[gid];
    int pos = atomicAdd(&cur[(size_t)t * (N + 1) + u], 1);
    col[(size_t)t * E + pos] = v;
}

// ---------------------------------------------------------------------------
extern "C" void kernel_launch(void* const* d_in, const int* in_sizes, int n_in,
                              void* d_out, int out_size, void* d_ws,
                              size_t ws_size, hipStream_t stream) {
    const float* ctrs = (const float*)d_in[0];
    const float* feats = (const float*)d_in[1];
    const float* in_W1 = (const float*)d_in[2];
    const float* in_b1 = (const float*)d_in[3];
    const float* in_W2 = (const float*)d_in[4];
    const float* in_b2 = (const float*)d_in[5];
    const float* seg_W1 = (const float*)d_in[6];
    const float* seg_b1 = (const float*)d_in[7];
    const float* seg_W2 = (const float*)d_in[8];
    const float* seg_b2 = (const float*)d_in[9];
    const float* embed = (const float*)d_in[10];
    const float* meta_W1 = (const float*)d_in[11];
    const float* meta_b1 = (const float*)d_in[12];
    const float* meta_W2 = (const float*)d_in[13];
    const float* meta_b2 = (const float*)d_in[14];
    const float* ctr_W = (const float*)d_in[15];
    const float* edge_W = (const float*)d_in[16];
    const float* norm_g = (const float*)d_in[17];
    const float* norm_b = (const float*)d_in[18];
    const float* ctr2_W1 = (const float*)d_in[19];
    const float* ctr2_b1 = (const float*)d_in[20];
    const float* ctr2_W2 = (const float*)d_in[21];
    const float* ctr2_b2 = (const float*)d_in[22];
    const int* mark_type = (const int*)d_in[23];
    const int* edge_u = (const int*)d_in[24];
    const int* edge_v = (const int*)d_in[25];

    const int N = in_sizes[0] / 2;
    const int E = in_sizes[24] / NT;
    const size_t ND = (size_t)N * D;
    const int nch = (N + SCH - 1) / SCH;

    // ws layout: [Wcvt 3.7MB | F 77MB | temp 77MB | rowptr 5.7 | col 5.7 | Yslots...]
    unsigned short* Wcvt = (unsigned short*)d_ws;
    size_t wcB = ((size_t)NMAT * MATSZ * sizeof(unsigned short) + 255) & ~(size_t)255;
    float* F = (float*)((char*)d_ws + wcB);
    float* temp = F + ND;
    int* rowptr = (int*)(temp + ND);
    int* col = rowptr + (size_t)NT * (N + 1);
    size_t base = (size_t)((char*)(col + (size_t)NT * E) - (char*)d_ws);
    base = (base + 255) & ~(size_t)255;
    float* Yws = (float*)((char*)d_ws + base);
    int extra = 0;
    if (ws_size > base + 256)
        extra = (int)((ws_size - base - 256) / (ND * sizeof(float)));
    int slots = 1 + (extra > 4 ? 4 : extra);  // slot0 = d_out (free mid-run)

    // weight conversion table
    CvtTab tab;
    tab.src[0] = in_W2;  tab.ldw[0] = D;
    tab.src[1] = seg_W2; tab.ldw[1] = D;
    for (int i = 0; i < NL; ++i) { tab.src[2 + i] = ctr2_W1 + (size_t)i * D * D; tab.ldw[2 + i] = D; }
    for (int i = 0; i < NL; ++i) { tab.src[6 + i] = ctr2_W2 + (size_t)i * D * D; tab.ldw[6 + i] = D; }
    for (int i = 0; i < NL; ++i) {
        for (int t = 0; t < NT; ++t) {
            int id = 10 + i * 11 + t;
            tab.src[id] = edge_W + ((size_t)i * NT + t) * D * D;
            tab.ldw[id] = D;
        }
        tab.src[10 + i * 11 + 10] = ctr_W + (size_t)i * D * D;
        tab.ldw[10 + i * 11 + 10] = D;
    }
    tab.src[54] = meta_W1;     tab.ldw[54] = 2 * D;
    tab.src[55] = meta_W1 + D; tab.ldw[55] = 2 * D;
    tab.src[56] = meta_W2;     tab.ldw[56] = D;
    wcvt_kernel<<<NMAT * 8, 256, 0, stream>>>(tab, Wcvt);

    dim3 blk(256);
    dim3 gTE(((size_t)NT * E + 255) / 256);
    dim3 g32((N * 32 + 255) / 256);
    dim3 g64(((size_t)N * 64 + 255) / 256);

    // CSR build (d_out is scratch here, freed after)
    {
        int* deg = (int*)d_out;
        int* cur = deg + (size_t)NT * N;
        int* csum = cur + (size_t)NT * (N + 1);
        hipMemsetAsync(deg, 0, (size_t)NT * N * sizeof(int), stream);
        csr_hist_kernel<<<gTE, blk, 0, stream>>>(edge_u, deg, N, E);
        csr_chunksum_kernel<<<NT * nch, blk, 0, stream>>>(deg, csum, N, nch);
        csr_chunkscan_kernel<<<1, 64, 0, stream>>>(csum, rowptr, N, nch);
        csr_blockscan_kernel<<<NT * nch, blk, 0, stream>>>(deg, csum, rowptr, cur, N, nch);
        csr_fill_kernel<<<gTE, blk, 0, stream>>>(edge_u, edge_v, cur, col, N, E);
    }

    float* slotp[5];
    slotp[0] = (float*)d_out;
    for (int i = 1; i < slots; ++i) slotp[i] = Yws + (size_t)(i - 1) * ND;

    // ---- input stage: F = relu(h1@W2in + b + h2@W2seg + b) ----
    {
        input_hidden_kernel<<<g32, blk, 0, stream>>>(ctrs, feats, in_W1, in_b1,
                                                     seg_W1, seg_b1, F,
                                                     (float*)d_out, N);
        OutP o{}; o.p[0] = F;
        launch_gemm(F, Wcvt + (size_t)0 * MATSZ, 1, o, in_b2, 0, nullptr, false, N, stream);
        launch_gemm((float*)d_out, Wcvt + (size_t)1 * MATSZ, 1, o, seg_b2, 0, F, true, N, stream);
    }

    // ---- fuse layers ----
    for (int i = 0; i < NL; ++i) {
        const unsigned short* WL = Wcvt + (size_t)(10 + i * 11) * MATSZ;
        OutP oc{}; oc.p[0] = temp;
        launch_gemm(F, WL + (size_t)10 * MATSZ, 1, oc, nullptr, 0, nullptr, false, N, stream);
        for (int g0 = 0; g0 < NT; g0 += slots) {
            int cnt = (NT - g0 < slots) ? (NT - g0) : slots;
            OutP oy{};
            InP iy{};
            for (int j = 0; j < cnt; ++j) { oy.p[j] = slotp[j]; iy.p[j] = slotp[j]; }
            launch_gemm(F, WL + (size_t)g0 * MATSZ, cnt, oy, nullptr, 0, nullptr, false, N, stream);
            bool last = (g0 + cnt == NT);
            if (last)
                csr_gather_multi_kernel<1><<<g64, blk, 0, stream>>>(
                    iy, rowptr + (size_t)g0 * (N + 1), col + (size_t)g0 * E,
                    temp, N, cnt, E, norm_g + (size_t)i * D,
                    norm_b + (size_t)i * D);
            else
                csr_gather_multi_kernel<0><<<g64, blk, 0, stream>>>(
                    iy, rowptr + (size_t)g0 * (N + 1), col + (size_t)g0 * E,
                    temp, N, cnt, E, nullptr, nullptr);
        }
        OutP oh{}; oh.p[0] = (float*)d_out;
        launch_gemm(temp, Wcvt + (size_t)(2 + i) * MATSZ, 1, oh,
                    ctr2_b1 + (size_t)i * D, 0, nullptr, true, N, stream);
        OutP of{}; of.p[0] = F;
        launch_gemm((float*)d_out, Wcvt + (size_t)(6 + i) * MATSZ, 1, of,
                    ctr2_b2 + (size_t)i * D, 0, F, true, N, stream);
    }

    // ---- meta stage ----
    {
        OutP ot{}; ot.p[0] = temp;
        launch_gemm(F, Wcvt + (size_t)54 * MATSZ, 1, ot, meta_b1, 0, nullptr, false, N, stream);
        gather_meta_kernel<<<g32, blk, 0, stream>>>(mark_type, embed, (float*)d_out, N);
        launch_gemm((float*)d_out, Wcvt + (size_t)55 * MATSZ, 1, ot, nullptr, 0, temp, true, N, stream);
        OutP oo{}; oo.p[0] = (float*)d_out;
        launch_gemm(temp, Wcvt + (size_t)56 * MATSZ, 1, oo, meta_b2, 0, nullptr, false, N, stream);
    }
}